// Round 5
// baseline (495.412 us; speedup 1.0000x reference)
//
#include <hip/hip_runtime.h>

#define BB 8
#define NN 1024
#define CC 64
#define TT 12
#define OO 64

typedef unsigned short u16;
typedef __attribute__((ext_vector_type(8))) short s16x8;
typedef __attribute__((ext_vector_type(4))) float f32x4;

__device__ __forceinline__ u16 f2bu(float f){
  union { float f; unsigned u; } v; v.f = f;
  unsigned r = v.u + 0x7FFFu + ((v.u >> 16) & 1u);
  return (u16)(r >> 16);
}
__device__ __forceinline__ float b2f(u16 h){
  union { unsigned u; float f; } v; v.u = ((unsigned)h) << 16; return v.f;
}
__device__ __forceinline__ float tanh_pos(float x){   // x >= 0
  float e = __expf(2.0f * x);
  return 1.0f - 2.0f * __builtin_amdgcn_rcpf(e + 1.0f);
}
__device__ __forceinline__ float tanh_sgn(float x){
  float t = tanh_pos(fabsf(x));
  return x < 0.0f ? -t : t;
}

#define MFMA16(a,b,c) __builtin_amdgcn_mfma_f32_16x16x32_bf16((a),(b),(c),0,0,0)

// frag load from padded-72 row-major LDS tile (row stride 144B = 9x16B, aligned)
__device__ __forceinline__ s16x8 ld72(const u16* s, int row0, int ko, int lane){
  return *(const s16x8*)(s + (row0 + (lane & 15)) * 72 + ko + ((lane >> 4) << 3));
}

// ---------------- K0: x [B,N,C,T] f32 -> xt [T,B,N,C] bf16 ----------------
__global__ __launch_bounds__(256) void k0_transpose(const float* __restrict__ x,
                                                    u16* __restrict__ xt){
  const int n = blockIdx.x, b = blockIdx.y;
  __shared__ float s[CC*TT];
  const float* src = x + (size_t)(b*NN + n)*CC*TT;
  for (int k = threadIdx.x; k < CC*TT; k += 256) s[k] = src[k];
  __syncthreads();
  for (int k = threadIdx.x; k < CC*TT; k += 256){
    const int t = k >> 6, c = k & 63;
    xt[(((size_t)t*BB + b)*NN + n)*CC + c] = f2bu(s[c*TT + t]);
  }
}

// ---------------- kadj: adj f32 -> bf16 ----------------
__global__ __launch_bounds__(256) void kadj(const float* __restrict__ adj,
                                            u16* __restrict__ adjb){
  const size_t i = ((size_t)blockIdx.x*256 + threadIdx.x)*4;
  const float4 v = *(const float4*)(adj + i);
  u16 o0=f2bu(v.x), o1=f2bu(v.y), o2=f2bu(v.z), o3=f2bu(v.w);
  adjb[i]=o0; adjb[i+1]=o1; adjb[i+2]=o2; adjb[i+3]=o3;
}

// ---- K1: base = xt@Wd + bd; DE1/2 = tanh(base*E1/2), direct stores ----
__global__ __launch_bounds__(256) void k1_de(const u16* __restrict__ xt,
    const float* __restrict__ Wd, const float* __restrict__ bd,
    const float* __restrict__ E1, const float* __restrict__ E2,
    u16* __restrict__ DE1g, u16* __restrict__ DE2g){
  __shared__ __align__(16) u16 sWd[64*72];   // W^T [o][c]
  const int tid = threadIdx.x, lane = tid & 63, wid = tid >> 6;
  const int l15 = lane & 15, lr4 = lane >> 4;
  const int it = blockIdx.x, b = blockIdx.y, t = blockIdx.z;
  const int n0 = it * 64;
  for (int k = tid; k < 4096; k += 256){
    const int o = k & 63, c = k >> 6;
    sWd[o*72 + c] = f2bu(Wd[(size_t)t*4096 + c*64 + o]);
  }
  __syncthreads();
  const size_t tb = (size_t)t*BB + b;
  const u16* gx = xt + (tb*NN + n0)*CC;
  const int wrow = wid * 16;
  const f32x4 fz = {0.f,0.f,0.f,0.f};
  f32x4 acc[4] = {fz, fz, fz, fz};
  #pragma unroll
  for (int ks = 0; ks < 2; ++ks){
    const int ko = ks*32;
    const s16x8 a = *(const s16x8*)(gx + (wrow + l15)*CC + ko + (lr4 << 3));
    #pragma unroll
    for (int v = 0; v < 4; ++v)
      acc[v] = MFMA16(a, ld72(sWd, v*16, ko, lane), acc[v]);
  }
  #pragma unroll
  for (int v = 0; v < 4; ++v){
    const int o = v*16 + l15;
    const float bdv = bd[t*OO + o];
    #pragma unroll
    for (int e = 0; e < 4; ++e){
      const int n = n0 + wrow + (lr4 << 2) + e;
      const float base = acc[v][e] + bdv;
      const size_t eo = ((size_t)t*NN + n)*OO + o;
      const size_t so = (tb*NN + n)*OO + o;
      DE1g[so] = f2bu(tanh_sgn(base * E1[eo]));
      DE2g[so] = f2bu(tanh_sgn(base * E2[eo]));
    }
  }
}

// ------- K23 (row-strip): A(i,:) = relu(tanh(Z1-Z2)) for a 64-row strip -------
// One block per (t,b,ti). DE_i staged once in LDS; A-frags live in regs; j-side
// B-frags stream direct-from-L2 with epilogue-overlap pipelining. Rowsum local.
__global__ __launch_bounds__(256) void k23(const u16* __restrict__ DE1g,
    const u16* __restrict__ DE2g, u16* __restrict__ Abuf,
    float* __restrict__ rowsum, int t0){
  __shared__ __align__(16) u16 s1[64*72], s2[64*72];       // 18.4KB
  __shared__ __align__(16) u16 bounce[2][4][16*72];        // 18KB (dbuf/wave)
  const int tid = threadIdx.x, lane = tid & 63, wid = tid >> 6;
  const int l15 = lane & 15, lr4 = lane >> 4;
  const int ti = blockIdx.x, b = blockIdx.y, t = t0 + blockIdx.z;
  const size_t tb = (size_t)t*BB + b;
  const u16* g1 = DE1g + tb*NN*OO;
  const u16* g2 = DE2g + tb*NN*OO;
  const int i0 = ti * 64;
  for (int k = tid; k < 512; k += 256){
    const int r = k >> 3, c = (k & 7) << 3;
    *(s16x8*)(s1 + r*72 + c) = *(const s16x8*)(g1 + (size_t)(i0 + r)*OO + c);
    *(s16x8*)(s2 + r*72 + c) = *(const s16x8*)(g2 + (size_t)(i0 + r)*OO + c);
  }
  __syncthreads();
  const int wrow = wid * 16;
  s16x8 a1[2], a2[2];
  #pragma unroll
  for (int ks = 0; ks < 2; ++ks){
    a1[ks] = ld72(s1, wrow, ks*32, lane);
    a2[ks] = ld72(s2, wrow, ks*32, lane);
  }
  u16* Ag = Abuf + ((size_t)blockIdx.z*BB + b)*NN*NN;
  const int grow0 = i0 + wrow + (lr4 << 2);   // this thread's 4 output rows
  float rp[4] = {0.f,0.f,0.f,0.f};
  const f32x4 fz = {0.f,0.f,0.f,0.f};
  s16x8 b1[8], b2[8];

#define PREF(TJ) do { \
    _Pragma("unroll") for (int ks = 0; ks < 2; ++ks) \
    _Pragma("unroll") for (int v = 0; v < 4; ++v){ \
      const int go = ((TJ)*64 + v*16 + l15)*OO + ks*32 + (lr4 << 3); \
      b1[ks*4+v] = *(const s16x8*)(g2 + go); \
      b2[ks*4+v] = *(const s16x8*)(g1 + go); \
    } } while (0)

  PREF(0);
  for (int tj = 0; tj < 16; ++tj){
    f32x4 z1[4], z2[4];
    #pragma unroll
    for (int v = 0; v < 4; ++v){ z1[v] = fz; z2[v] = fz; }
    #pragma unroll
    for (int ks = 0; ks < 2; ++ks)
      #pragma unroll
      for (int v = 0; v < 4; ++v){
        z1[v] = MFMA16(a1[ks], b1[ks*4+v], z1[v]);
        z2[v] = MFMA16(a2[ks], b2[ks*4+v], z2[v]);
      }
    if (tj < 15) PREF(tj + 1);          // loads fly under the tanh/store phase
    u16* wb = bounce[tj & 1][wid];
    #pragma unroll
    for (int v = 0; v < 4; ++v)
      #pragma unroll
      for (int e = 0; e < 4; ++e){
        const float d = z1[v][e] - z2[v][e];
        const float tt = tanh_pos(fabsf(d));
        float q = d > 0.f ? tt : 0.f;
        rp[e] += q;
        if (grow0 + e == tj*64 + v*16 + l15) q += 1.0f;   // fold identity
        wb[((lr4 << 2) + e)*72 + v*16 + l15] = f2bu(q);
      }
    asm volatile("s_waitcnt lgkmcnt(0)" ::: "memory");
    __builtin_amdgcn_sched_barrier(0);
    #pragma unroll
    for (int h = 0; h < 2; ++h){
      const int idx = h*64 + lane;
      const int r = idx >> 3, c = (idx & 7) << 3;
      *(s16x8*)(Ag + (size_t)(i0 + wrow + r)*NN + tj*64 + c) =
          *(const s16x8*)(wb + r*72 + c);
    }
  }
#undef PREF
  #pragma unroll
  for (int e = 0; e < 4; ++e){
    float r = rp[e];
    r += __shfl_xor(r, 1); r += __shfl_xor(r, 2);
    r += __shfl_xor(r, 4); r += __shfl_xor(r, 8);
    if (l15 == 0) rowsum[tb*NN + grow0 + e] = r + 1.0f;   // +I
  }
}

// ---- K3b: xdw' = 0.475*dis*x@Wd ; xsw' = 0.475*x@Ws  (stored [o][n] bf16)
//      x0w = 0.05*x@W0 + all biases (stored natural [n][o] bf16) ----
__global__ __launch_bounds__(256) void k3b(const u16* __restrict__ xt,
    const float* __restrict__ Wd, const float* __restrict__ Ws,
    const float* __restrict__ W0, const float* __restrict__ bd,
    const float* __restrict__ bs, const float* __restrict__ b0,
    const float* __restrict__ rowsum, u16* __restrict__ xdwT,
    u16* __restrict__ xswT, u16* __restrict__ x0w, int t0){
  __shared__ __align__(16) u16 sW[64*72];
  const int tid = threadIdx.x, lane = tid & 63, wid = tid >> 6;
  const int l15 = lane & 15, lr4 = lane >> 4;
  const int it = blockIdx.x, b = blockIdx.y, t = t0 + blockIdx.z;
  const size_t tb = (size_t)t*BB + b;
  const int n0 = it * 128, wrow = wid * 32;
  const float* rsb = rowsum + tb*NN + n0;
  float dis[2][4];
  #pragma unroll
  for (int u = 0; u < 2; ++u)
    #pragma unroll
    for (int e = 0; e < 4; ++e)
      dis[u][e] = rsqrtf(rsb[wrow + u*16 + (lr4 << 2) + e]);
  float badd[4];
  #pragma unroll
  for (int v = 0; v < 4; ++v){
    const int o = v*16 + l15;
    badd[v] = 0.475f*(bd[t*OO + o] + bs[t*OO + o]) + 0.05f*b0[o];
  }
  const u16* gx = xt + (tb*NN + n0)*CC;
  const f32x4 fz = {0.f,0.f,0.f,0.f};
  for (int pass = 0; pass < 3; ++pass){
    __syncthreads();
    {
      const float* Wsrc = (pass == 0) ? (Wd + (size_t)t*4096)
                        : (pass == 1) ? (Ws + (size_t)t*4096) : W0;
      const float scale = (pass == 2) ? 0.05f : 0.475f;
      for (int k = tid; k < 4096; k += 256){
        const int o = k & 63, c = k >> 6;
        sW[o*72 + c] = f2bu(scale * Wsrc[c*64 + o]);
      }
    }
    __syncthreads();
    f32x4 acc[2][4];
    #pragma unroll
    for (int u = 0; u < 2; ++u)
      #pragma unroll
      for (int v = 0; v < 4; ++v) acc[u][v] = fz;
    #pragma unroll
    for (int ks = 0; ks < 2; ++ks){
      const int ko = ks*32;
      s16x8 bw[4];
      #pragma unroll
      for (int v = 0; v < 4; ++v) bw[v] = ld72(sW, v*16, ko, lane);
      #pragma unroll
      for (int u = 0; u < 2; ++u){
        const s16x8 a = *(const s16x8*)(gx + (wrow + u*16 + l15)*CC + ko + (lr4 << 3));
        #pragma unroll
        for (int v = 0; v < 4; ++v) acc[u][v] = MFMA16(a, bw[v], acc[u][v]);
      }
    }
    #pragma unroll
    for (int u = 0; u < 2; ++u)
      #pragma unroll
      for (int v = 0; v < 4; ++v){
        const int o = v*16 + l15;
        #pragma unroll
        for (int e = 0; e < 4; ++e){
          const int nl = wrow + u*16 + (lr4 << 2) + e;
          float val = acc[u][v][e];
          if (pass == 0){
            xdwT[(tb*OO + o)*NN + n0 + nl] = f2bu(val * dis[u][e]);
          } else if (pass == 1){
            xswT[(tb*OO + o)*NN + n0 + nl] = f2bu(val);
          } else {
            x0w[(tb*NN + n0 + nl)*OO + o] = f2bu(val + badd[v]);
          }
        }
      }
  }
}

// ---- K4: outT = dis_i*((A+I)@xdw') + adj@xsw'
//      double-buffered swizzled LDS staging of A/J; B direct-global (L2-hot) ----
__global__ __launch_bounds__(512) void k4(const u16* __restrict__ Abuf,
    const u16* __restrict__ adjb, const u16* __restrict__ xdwT,
    const u16* __restrict__ xswT, const float* __restrict__ rowsum,
    float* __restrict__ outT, int t0){
  __shared__ __align__(16) u16 sA[2][128*64];   // 32KB (swizzled rows)
  __shared__ __align__(16) u16 sJ[2][128*64];   // 32KB
  const int tid = threadIdx.x, lane = tid & 63, wid = tid >> 6;
  const int l15 = lane & 15, lr4 = lane >> 4;
  const int it = blockIdx.x, b = blockIdx.y, tl = blockIdx.z, t = t0 + tl;
  const size_t tb = (size_t)t*BB + b;
  const u16* Ag = Abuf + ((size_t)tl*BB + b)*NN*NN;
  const u16* xd = xdwT + tb*OO*NN;
  const u16* xs = xswT + tb*OO*NN;
  const int i0 = it * 128, wrow = wid * 16;
  const int srow = tid >> 2;
  const int scb  = (tid & 3) * 32;               // byte col base in row
  const int wb0 = srow*128 + ((scb     ) ^ ((srow & 7) << 4));
  const int wb1 = srow*128 + ((scb + 16) ^ ((srow & 7) << 4));
  const u16* gaRow = Ag   + (size_t)(i0 + srow)*NN + (scb >> 1);
  const u16* gjRow = adjb + (size_t)(i0 + srow)*NN + (scb >> 1);
  const int frow = wrow + l15;
  const int swzr = (frow & 7) << 4;
  const int rbase = frow * 128;
  s16x8 pA0, pA1, pJ0, pJ1;
  pA0 = *(const s16x8*)(gaRow);     pA1 = *(const s16x8*)(gaRow + 8);
  pJ0 = *(const s16x8*)(gjRow);     pJ1 = *(const s16x8*)(gjRow + 8);
  *(s16x8*)((char*)sA[0] + wb0) = pA0;  *(s16x8*)((char*)sA[0] + wb1) = pA1;
  *(s16x8*)((char*)sJ[0] + wb0) = pJ0;  *(s16x8*)((char*)sJ[0] + wb1) = pJ1;
  __syncthreads();
  const f32x4 fz = {0.f,0.f,0.f,0.f};
  f32x4 ad[4] = {fz,fz,fz,fz}, as_[4] = {fz,fz,fz,fz};
  for (int tj = 0; tj < 16; ++tj){
    const int cur = tj & 1;
    const int j0 = tj * 64;
    if (tj < 15){                                 // T14: issue next-tile loads early
      pA0 = *(const s16x8*)(gaRow + j0 + 64);
      pA1 = *(const s16x8*)(gaRow + j0 + 72);
      pJ0 = *(const s16x8*)(gjRow + j0 + 64);
      pJ1 = *(const s16x8*)(gjRow + j0 + 72);
    }
    #pragma unroll
    for (int ks = 0; ks < 2; ++ks){
      const int ko = j0 + ks*32 + (lr4 << 3);
      s16x8 bD[4], bS[4];
      #pragma unroll
      for (int v = 0; v < 4; ++v){
        bD[v] = *(const s16x8*)(xd + (size_t)(v*16 + l15)*NN + ko);
        bS[v] = *(const s16x8*)(xs + (size_t)(v*16 + l15)*NN + ko);
      }
      const int rb = rbase + (((ks*32 + (lr4 << 3)) << 1) ^ swzr);
      const s16x8 aA = *(const s16x8*)((const char*)sA[cur] + rb);
      const s16x8 aJ = *(const s16x8*)((const char*)sJ[cur] + rb);
      #pragma unroll
      for (int v = 0; v < 4; ++v){
        ad[v]  = MFMA16(aA, bD[v], ad[v]);
        as_[v] = MFMA16(aJ, bS[v], as_[v]);
      }
    }
    if (tj < 15){
      const int nxt = cur ^ 1;
      *(s16x8*)((char*)sA[nxt] + wb0) = pA0;  *(s16x8*)((char*)sA[nxt] + wb1) = pA1;
      *(s16x8*)((char*)sJ[nxt] + wb0) = pJ0;  *(s16x8*)((char*)sJ[nxt] + wb1) = pJ1;
      __syncthreads();
    }
  }
  const float* rsb = rowsum + tb*NN + i0;
  float dis[4];
  #pragma unroll
  for (int e = 0; e < 4; ++e)
    dis[e] = rsqrtf(rsb[wrow + (lr4 << 2) + e]);
  #pragma unroll
  for (int v = 0; v < 4; ++v){
    const int o = v*16 + l15;
    const int nl = i0 + wrow + (lr4 << 2);
    #pragma unroll
    for (int e = 0; e < 4; ++e)
      outT[(tb*NN + nl + e)*OO + o] = dis[e]*ad[v][e] + as_[v][e];
  }
}

// ---------------- K5: out = transpose(outT + x0w) -> [B,N,O,T] ----------
__global__ __launch_bounds__(256) void k5(const float* __restrict__ outT,
                                          const u16* __restrict__ x0w,
                                          float* __restrict__ out){
  __shared__ float s[16*64*12];
  const int tid = threadIdx.x;
  const int nb = blockIdx.x, b = blockIdx.y;
  const int n0 = nb * 16;
  for (int t = 0; t < TT; ++t){
    for (int k = tid; k < 1024; k += 256){
      const int r = k >> 6, o = k & 63;
      const size_t idx = (((size_t)t*BB + b)*NN + n0 + r)*OO + o;
      s[(r*64 + o)*12 + t] = outT[idx] + b2f(x0w[idx]);
    }
  }
  __syncthreads();
  float* dst = out + (size_t)(b*NN + n0)*OO*TT;
  for (int k = tid; k < 16*64*12; k += 256) dst[k] = s[k];
}

extern "C" void kernel_launch(void* const* d_in, const int* in_sizes, int n_in,
                              void* d_out, int out_size, void* d_ws, size_t ws_size,
                              hipStream_t stream) {
  const float* x   = (const float*)d_in[0];
  const float* adj = (const float*)d_in[1];
  const float* W0  = (const float*)d_in[2];
  const float* b0  = (const float*)d_in[3];
  const float* Ws  = (const float*)d_in[4];
  const float* bs  = (const float*)d_in[5];
  const float* Wd  = (const float*)d_in[6];
  const float* bd  = (const float*)d_in[7];
  const float* E1  = (const float*)d_in[8];
  const float* E2  = (const float*)d_in[9];
  float* out = (float*)d_out;

  char* w = (char*)d_ws;
  size_t off = 0;
  auto take = [&](size_t bytes) -> char* {
    char* p = w + off;
    off += bytes; off = (off + 255) & ~(size_t)255;
    return p;
  };
  const size_t NE = (size_t)TT*BB*NN*OO;
  u16*   xt    = (u16*)  take(NE*2);
  u16*   adjb  = (u16*)  take((size_t)NN*NN*2);
  u16*   DE1   = (u16*)  take(NE*2);
  u16*   DE2   = (u16*)  take(NE*2);
  float* rowsum= (float*)take((size_t)TT*BB*NN*4);
  u16*   xdwT  = (u16*)  take(NE*2);
  u16*   xswT  = (u16*)  take(NE*2);
  u16*   x0w   = (u16*)  take(NE*2);
  float* outT  = (float*)take(NE*4);
  const size_t perT = (size_t)BB*NN*NN*2;
  size_t rem = (ws_size > off) ? (ws_size - off) : 0;
  int tc = (int)(rem / perT);
  if (tc < 1) tc = 1;
  if (tc > 4) tc = 4;          // keep Abuf (<=67MB) L3-resident

  u16* Abuf = (u16*)(w + off);

  k0_transpose<<<dim3(NN, BB), 256, 0, stream>>>(x, xt);
  kadj<<<dim3((NN*NN)/1024), 256, 0, stream>>>(adj, adjb);
  k1_de<<<dim3(16, BB, TT), 256, 0, stream>>>(xt, Wd, bd, E1, E2, DE1, DE2);

  for (int t0 = 0; t0 < TT; t0 += tc){
    const int nt = (t0 + tc <= TT) ? tc : (TT - t0);
    k23<<<dim3(16, BB, nt), 256, 0, stream>>>(DE1, DE2, Abuf, rowsum, t0);
    k3b<<<dim3(8, BB, nt), 256, 0, stream>>>(xt, Wd, Ws, W0, bd, bs, b0,
                                             rowsum, xdwT, xswT, x0w, t0);
    k4 <<<dim3(8, BB, nt), 512, 0, stream>>>(Abuf, adjb, xdwT, xswT,
                                             rowsum, outT, t0);
  }
  k5<<<dim3(NN/16, BB), 256, 0, stream>>>(outT, x0w, out);
}

// Round 6
// 354.883 us; speedup vs baseline: 1.3960x; 1.3960x over previous
//
#include <hip/hip_runtime.h>

#define BB 8
#define NN 1024
#define CC 64
#define TT 12
#define OO 64

typedef unsigned short u16;
typedef __attribute__((ext_vector_type(8))) short s16x8;
typedef __attribute__((ext_vector_type(4))) float f32x4;

__device__ __forceinline__ u16 f2bu(float f){
  union { float f; unsigned u; } v; v.f = f;
  unsigned r = v.u + 0x7FFFu + ((v.u >> 16) & 1u);
  return (u16)(r >> 16);
}
__device__ __forceinline__ float b2f(u16 h){
  union { unsigned u; float f; } v; v.u = ((unsigned)h) << 16; return v.f;
}
__device__ __forceinline__ float tanh_pos(float x){   // x >= 0
  float e = __expf(2.0f * x);
  return 1.0f - 2.0f * __builtin_amdgcn_rcpf(e + 1.0f);
}
__device__ __forceinline__ float tanh_sgn(float x){
  float t = tanh_pos(fabsf(x));
  return x < 0.0f ? -t : t;
}

#define MFMA16(a,b,c) __builtin_amdgcn_mfma_f32_16x16x32_bf16((a),(b),(c),0,0,0)

// frag load from padded-72 row-major LDS tile (row stride 144B = 9x16B, aligned)
__device__ __forceinline__ s16x8 ld72(const u16* s, int row0, int ko, int lane){
  return *(const s16x8*)(s + (row0 + (lane & 15)) * 72 + ko + ((lane >> 4) << 3));
}

// ---------------- K0: x [B,N,C,T] f32 -> xt [T,B,N,C] bf16 ----------------
__global__ __launch_bounds__(256) void k0_transpose(const float* __restrict__ x,
                                                    u16* __restrict__ xt){
  const int n = blockIdx.x, b = blockIdx.y;
  __shared__ float s[CC*TT];
  const float* src = x + (size_t)(b*NN + n)*CC*TT;
  for (int k = threadIdx.x; k < CC*TT; k += 256) s[k] = src[k];
  __syncthreads();
  for (int k = threadIdx.x; k < CC*TT; k += 256){
    const int t = k >> 6, c = k & 63;
    xt[(((size_t)t*BB + b)*NN + n)*CC + c] = f2bu(s[c*TT + t]);
  }
}

// ---------------- kadj: adj f32 -> bf16 ----------------
__global__ __launch_bounds__(256) void kadj(const float* __restrict__ adj,
                                            u16* __restrict__ adjb){
  const size_t i = ((size_t)blockIdx.x*256 + threadIdx.x)*4;
  const float4 v = *(const float4*)(adj + i);
  u16 o0=f2bu(v.x), o1=f2bu(v.y), o2=f2bu(v.z), o3=f2bu(v.w);
  adjb[i]=o0; adjb[i+1]=o1; adjb[i+2]=o2; adjb[i+3]=o3;
}

// ---- K1: base = xt@Wd + bd; DE1/2 = tanh(base*E1/2), direct stores ----
__global__ __launch_bounds__(256) void k1_de(const u16* __restrict__ xt,
    const float* __restrict__ Wd, const float* __restrict__ bd,
    const float* __restrict__ E1, const float* __restrict__ E2,
    u16* __restrict__ DE1g, u16* __restrict__ DE2g){
  __shared__ __align__(16) u16 sWd[64*72];   // W^T [o][c]
  const int tid = threadIdx.x, lane = tid & 63, wid = tid >> 6;
  const int l15 = lane & 15, lr4 = lane >> 4;
  const int it = blockIdx.x, b = blockIdx.y, t = blockIdx.z;
  const int n0 = it * 64;
  for (int k = tid; k < 4096; k += 256){
    const int o = k & 63, c = k >> 6;
    sWd[o*72 + c] = f2bu(Wd[(size_t)t*4096 + c*64 + o]);
  }
  __syncthreads();
  const size_t tb = (size_t)t*BB + b;
  const u16* gx = xt + (tb*NN + n0)*CC;
  const int wrow = wid * 16;
  const f32x4 fz = {0.f,0.f,0.f,0.f};
  f32x4 acc[4] = {fz, fz, fz, fz};
  #pragma unroll
  for (int ks = 0; ks < 2; ++ks){
    const int ko = ks*32;
    const s16x8 a = *(const s16x8*)(gx + (wrow + l15)*CC + ko + (lr4 << 3));
    #pragma unroll
    for (int v = 0; v < 4; ++v)
      acc[v] = MFMA16(a, ld72(sWd, v*16, ko, lane), acc[v]);
  }
  #pragma unroll
  for (int v = 0; v < 4; ++v){
    const int o = v*16 + l15;
    const float bdv = bd[t*OO + o];
    #pragma unroll
    for (int e = 0; e < 4; ++e){
      const int n = n0 + wrow + (lr4 << 2) + e;
      const float base = acc[v][e] + bdv;
      const size_t eo = ((size_t)t*NN + n)*OO + o;
      const size_t so = (tb*NN + n)*OO + o;
      DE1g[so] = f2bu(tanh_sgn(base * E1[eo]));
      DE2g[so] = f2bu(tanh_sgn(base * E2[eo]));
    }
  }
}

// ------- K23 (row-strip): A(i,:) = relu(tanh(Z1-Z2)) for a 64-row strip -------
__global__ __launch_bounds__(256) void k23(const u16* __restrict__ DE1g,
    const u16* __restrict__ DE2g, u16* __restrict__ Abuf,
    float* __restrict__ rowsum, int t0){
  __shared__ __align__(16) u16 s1[64*72], s2[64*72];       // 18.4KB
  __shared__ __align__(16) u16 bounce[2][4][16*72];        // 18KB (dbuf/wave)
  const int tid = threadIdx.x, lane = tid & 63, wid = tid >> 6;
  const int l15 = lane & 15, lr4 = lane >> 4;
  const int ti = blockIdx.x, b = blockIdx.y, t = t0 + blockIdx.z;
  const size_t tb = (size_t)t*BB + b;
  const u16* g1 = DE1g + tb*NN*OO;
  const u16* g2 = DE2g + tb*NN*OO;
  const int i0 = ti * 64;
  for (int k = tid; k < 512; k += 256){
    const int r = k >> 3, c = (k & 7) << 3;
    *(s16x8*)(s1 + r*72 + c) = *(const s16x8*)(g1 + (size_t)(i0 + r)*OO + c);
    *(s16x8*)(s2 + r*72 + c) = *(const s16x8*)(g2 + (size_t)(i0 + r)*OO + c);
  }
  __syncthreads();
  const int wrow = wid * 16;
  s16x8 a1[2], a2[2];
  #pragma unroll
  for (int ks = 0; ks < 2; ++ks){
    a1[ks] = ld72(s1, wrow, ks*32, lane);
    a2[ks] = ld72(s2, wrow, ks*32, lane);
  }
  u16* Ag = Abuf + ((size_t)blockIdx.z*BB + b)*NN*NN;
  const int grow0 = i0 + wrow + (lr4 << 2);   // this thread's 4 output rows
  float rp[4] = {0.f,0.f,0.f,0.f};
  const f32x4 fz = {0.f,0.f,0.f,0.f};
  s16x8 b1[8], b2[8];

#define PREF(TJ) do { \
    _Pragma("unroll") for (int ks = 0; ks < 2; ++ks) \
    _Pragma("unroll") for (int v = 0; v < 4; ++v){ \
      const int go = ((TJ)*64 + v*16 + l15)*OO + ks*32 + (lr4 << 3); \
      b1[ks*4+v] = *(const s16x8*)(g2 + go); \
      b2[ks*4+v] = *(const s16x8*)(g1 + go); \
    } } while (0)

  PREF(0);
  for (int tj = 0; tj < 16; ++tj){
    f32x4 z1[4], z2[4];
    #pragma unroll
    for (int v = 0; v < 4; ++v){ z1[v] = fz; z2[v] = fz; }
    #pragma unroll
    for (int ks = 0; ks < 2; ++ks)
      #pragma unroll
      for (int v = 0; v < 4; ++v){
        z1[v] = MFMA16(a1[ks], b1[ks*4+v], z1[v]);
        z2[v] = MFMA16(a2[ks], b2[ks*4+v], z2[v]);
      }
    if (tj < 15) PREF(tj + 1);          // loads fly under the tanh/store phase
    u16* wb = bounce[tj & 1][wid];
    #pragma unroll
    for (int v = 0; v < 4; ++v)
      #pragma unroll
      for (int e = 0; e < 4; ++e){
        const float d = z1[v][e] - z2[v][e];
        const float tt = tanh_pos(fabsf(d));
        float q = d > 0.f ? tt : 0.f;
        rp[e] += q;
        if (grow0 + e == tj*64 + v*16 + l15) q += 1.0f;   // fold identity
        wb[((lr4 << 2) + e)*72 + v*16 + l15] = f2bu(q);
      }
    asm volatile("s_waitcnt lgkmcnt(0)" ::: "memory");
    __builtin_amdgcn_sched_barrier(0);
    #pragma unroll
    for (int h = 0; h < 2; ++h){
      const int idx = h*64 + lane;
      const int r = idx >> 3, c = (idx & 7) << 3;
      *(s16x8*)(Ag + (size_t)(i0 + wrow + r)*NN + tj*64 + c) =
          *(const s16x8*)(wb + r*72 + c);
    }
  }
#undef PREF
  #pragma unroll
  for (int e = 0; e < 4; ++e){
    float r = rp[e];
    r += __shfl_xor(r, 1); r += __shfl_xor(r, 2);
    r += __shfl_xor(r, 4); r += __shfl_xor(r, 8);
    if (l15 == 0) rowsum[tb*NN + grow0 + e] = r + 1.0f;   // +I
  }
}

// ---- K3b: xdw' = 0.475*dis*x@Wd ; xsw' = 0.475*x@Ws  (stored [o][n] bf16)
//      x0w = 0.05*x@W0 + all biases (stored natural [n][o] bf16) ----
__global__ __launch_bounds__(256) void k3b(const u16* __restrict__ xt,
    const float* __restrict__ Wd, const float* __restrict__ Ws,
    const float* __restrict__ W0, const float* __restrict__ bd,
    const float* __restrict__ bs, const float* __restrict__ b0,
    const float* __restrict__ rowsum, u16* __restrict__ xdwT,
    u16* __restrict__ xswT, u16* __restrict__ x0w, int t0){
  __shared__ __align__(16) u16 sW[64*72];
  const int tid = threadIdx.x, lane = tid & 63, wid = tid >> 6;
  const int l15 = lane & 15, lr4 = lane >> 4;
  const int it = blockIdx.x, b = blockIdx.y, t = t0 + blockIdx.z;
  const size_t tb = (size_t)t*BB + b;
  const int n0 = it * 128, wrow = wid * 32;
  const float* rsb = rowsum + tb*NN + n0;
  float dis[2][4];
  #pragma unroll
  for (int u = 0; u < 2; ++u)
    #pragma unroll
    for (int e = 0; e < 4; ++e)
      dis[u][e] = rsqrtf(rsb[wrow + u*16 + (lr4 << 2) + e]);
  float badd[4];
  #pragma unroll
  for (int v = 0; v < 4; ++v){
    const int o = v*16 + l15;
    badd[v] = 0.475f*(bd[t*OO + o] + bs[t*OO + o]) + 0.05f*b0[o];
  }
  const u16* gx = xt + (tb*NN + n0)*CC;
  const f32x4 fz = {0.f,0.f,0.f,0.f};
  for (int pass = 0; pass < 3; ++pass){
    __syncthreads();
    {
      const float* Wsrc = (pass == 0) ? (Wd + (size_t)t*4096)
                        : (pass == 1) ? (Ws + (size_t)t*4096) : W0;
      const float scale = (pass == 2) ? 0.05f : 0.475f;
      for (int k = tid; k < 4096; k += 256){
        const int o = k & 63, c = k >> 6;
        sW[o*72 + c] = f2bu(scale * Wsrc[c*64 + o]);
      }
    }
    __syncthreads();
    f32x4 acc[2][4];
    #pragma unroll
    for (int u = 0; u < 2; ++u)
      #pragma unroll
      for (int v = 0; v < 4; ++v) acc[u][v] = fz;
    #pragma unroll
    for (int ks = 0; ks < 2; ++ks){
      const int ko = ks*32;
      s16x8 bw[4];
      #pragma unroll
      for (int v = 0; v < 4; ++v) bw[v] = ld72(sW, v*16, ko, lane);
      #pragma unroll
      for (int u = 0; u < 2; ++u){
        const s16x8 a = *(const s16x8*)(gx + (wrow + u*16 + l15)*CC + ko + (lr4 << 3));
        #pragma unroll
        for (int v = 0; v < 4; ++v) acc[u][v] = MFMA16(a, bw[v], acc[u][v]);
      }
    }
    #pragma unroll
    for (int u = 0; u < 2; ++u)
      #pragma unroll
      for (int v = 0; v < 4; ++v){
        const int o = v*16 + l15;
        #pragma unroll
        for (int e = 0; e < 4; ++e){
          const int nl = wrow + u*16 + (lr4 << 2) + e;
          float val = acc[u][v][e];
          if (pass == 0){
            xdwT[(tb*OO + o)*NN + n0 + nl] = f2bu(val * dis[u][e]);
          } else if (pass == 1){
            xswT[(tb*OO + o)*NN + n0 + nl] = f2bu(val);
          } else {
            x0w[(tb*NN + n0 + nl)*OO + o] = f2bu(val + badd[v]);
          }
        }
      }
  }
}

// ---- K4: outT = dis_i*((A+I)@xdw') + adj@xsw'
//      ALL operands LDS-staged (padded-72), dbuf, depth-2 register pipeline ----
__global__ __launch_bounds__(512) void k4(const u16* __restrict__ Abuf,
    const u16* __restrict__ adjb, const u16* __restrict__ xdwT,
    const u16* __restrict__ xswT, const float* __restrict__ rowsum,
    float* __restrict__ outT, int t0){
  __shared__ __align__(16) u16 sA[2][128*72];   // 36KB
  __shared__ __align__(16) u16 sJ[2][128*72];   // 36KB
  __shared__ __align__(16) u16 sD[2][64*72];    // 18KB
  __shared__ __align__(16) u16 sS[2][64*72];    // 18KB  (total 108KB)
  const int tid = threadIdx.x, lane = tid & 63, wid = tid >> 6;
  const int l15 = lane & 15, lr4 = lane >> 4;
  const int it = blockIdx.x, b = blockIdx.y, tl = blockIdx.z, t = t0 + tl;
  const size_t tb = (size_t)t*BB + b;
  const u16* Ag = Abuf + ((size_t)tl*BB + b)*NN*NN;
  const u16* xd = xdwT + tb*OO*NN;
  const u16* xs = xswT + tb*OO*NN;
  const int i0 = it * 128, wrow = wid * 16;
  // staging maps: A/J 128 rows x (2x16B); D/S 64 rows x 16B
  const int arow = tid >> 2, ac0 = (tid & 3) * 16;
  const int drow = tid >> 3, dc0 = (tid & 7) * 8;
  const u16* gA = Ag   + (size_t)(i0 + arow)*NN + ac0;
  const u16* gJ = adjb + (size_t)(i0 + arow)*NN + ac0;
  const u16* gD = xd + (size_t)drow*NN + dc0;
  const u16* gS = xs + (size_t)drow*NN + dc0;
  s16x8 pr[2][6];
#define K4LOAD(P, TJ) do { \
    pr[P][0] = *(const s16x8*)(gA + (TJ)*64); \
    pr[P][1] = *(const s16x8*)(gA + (TJ)*64 + 8); \
    pr[P][2] = *(const s16x8*)(gJ + (TJ)*64); \
    pr[P][3] = *(const s16x8*)(gJ + (TJ)*64 + 8); \
    pr[P][4] = *(const s16x8*)(gD + (TJ)*64); \
    pr[P][5] = *(const s16x8*)(gS + (TJ)*64); \
  } while (0)
#define K4WRITE(BUF, P) do { \
    *(s16x8*)(sA[BUF] + arow*72 + ac0)     = pr[P][0]; \
    *(s16x8*)(sA[BUF] + arow*72 + ac0 + 8) = pr[P][1]; \
    *(s16x8*)(sJ[BUF] + arow*72 + ac0)     = pr[P][2]; \
    *(s16x8*)(sJ[BUF] + arow*72 + ac0 + 8) = pr[P][3]; \
    *(s16x8*)(sD[BUF] + drow*72 + dc0)     = pr[P][4]; \
    *(s16x8*)(sS[BUF] + drow*72 + dc0)     = pr[P][5]; \
  } while (0)
  K4LOAD(0, 0);
  K4WRITE(0, 0);
  K4LOAD(1, 1);
  __syncthreads();
  const f32x4 fz = {0.f,0.f,0.f,0.f};
  f32x4 ad[4] = {fz,fz,fz,fz}, as_[4] = {fz,fz,fz,fz};
  #pragma unroll
  for (int tj = 0; tj < 16; ++tj){
    const int cur = tj & 1;
    if (tj < 14) K4LOAD(cur, tj + 2);     // regs freed by last iter's WRITE
    #pragma unroll
    for (int ks = 0; ks < 2; ++ks){
      const int ko = ks*32;
      s16x8 bD[4], bS[4];
      #pragma unroll
      for (int v = 0; v < 4; ++v){
        bD[v] = ld72(sD[cur], v*16, ko, lane);
        bS[v] = ld72(sS[cur], v*16, ko, lane);
      }
      const s16x8 aA = ld72(sA[cur], wrow, ko, lane);
      const s16x8 aJ = ld72(sJ[cur], wrow, ko, lane);
      #pragma unroll
      for (int v = 0; v < 4; ++v){
        ad[v]  = MFMA16(aA, bD[v], ad[v]);
        as_[v] = MFMA16(aJ, bS[v], as_[v]);
      }
    }
    if (tj < 15) K4WRITE(cur ^ 1, (tj + 1) & 1);   // vmcnt covered by compute
    __syncthreads();
  }
#undef K4LOAD
#undef K4WRITE
  const float* rsb = rowsum + tb*NN + i0;
  float dis[4];
  #pragma unroll
  for (int e = 0; e < 4; ++e)
    dis[e] = rsqrtf(rsb[wrow + (lr4 << 2) + e]);
  #pragma unroll
  for (int v = 0; v < 4; ++v){
    const int o = v*16 + l15;
    const int nl = i0 + wrow + (lr4 << 2);
    #pragma unroll
    for (int e = 0; e < 4; ++e)
      outT[(tb*NN + nl + e)*OO + o] = dis[e]*ad[v][e] + as_[v][e];
  }
}

// ---------------- K5: out = transpose(outT + x0w) -> [B,N,O,T] ----------
__global__ __launch_bounds__(256) void k5(const float* __restrict__ outT,
                                          const u16* __restrict__ x0w,
                                          float* __restrict__ out){
  __shared__ float s[16*64*12];
  const int tid = threadIdx.x;
  const int nb = blockIdx.x, b = blockIdx.y;
  const int n0 = nb * 16;
  for (int t = 0; t < TT; ++t){
    for (int k = tid; k < 1024; k += 256){
      const int r = k >> 6, o = k & 63;
      const size_t idx = (((size_t)t*BB + b)*NN + n0 + r)*OO + o;
      s[(r*64 + o)*12 + t] = outT[idx] + b2f(x0w[idx]);
    }
  }
  __syncthreads();
  float* dst = out + (size_t)(b*NN + n0)*OO*TT;
  for (int k = tid; k < 16*64*12; k += 256) dst[k] = s[k];
}

extern "C" void kernel_launch(void* const* d_in, const int* in_sizes, int n_in,
                              void* d_out, int out_size, void* d_ws, size_t ws_size,
                              hipStream_t stream) {
  const float* x   = (const float*)d_in[0];
  const float* adj = (const float*)d_in[1];
  const float* W0  = (const float*)d_in[2];
  const float* b0  = (const float*)d_in[3];
  const float* Ws  = (const float*)d_in[4];
  const float* bs  = (const float*)d_in[5];
  const float* Wd  = (const float*)d_in[6];
  const float* bd  = (const float*)d_in[7];
  const float* E1  = (const float*)d_in[8];
  const float* E2  = (const float*)d_in[9];
  float* out = (float*)d_out;

  char* w = (char*)d_ws;
  size_t off = 0;
  auto take = [&](size_t bytes) -> char* {
    char* p = w + off;
    off += bytes; off = (off + 255) & ~(size_t)255;
    return p;
  };
  const size_t NE = (size_t)TT*BB*NN*OO;
  u16*   xt    = (u16*)  take(NE*2);
  u16*   adjb  = (u16*)  take((size_t)NN*NN*2);
  u16*   DE1   = (u16*)  take(NE*2);
  u16*   DE2   = (u16*)  take(NE*2);
  float* rowsum= (float*)take((size_t)TT*BB*NN*4);
  u16*   xdwT  = (u16*)  take(NE*2);
  u16*   xswT  = (u16*)  take(NE*2);
  u16*   x0w   = (u16*)  take(NE*2);
  float* outT  = (float*)take(NE*4);
  const size_t perT = (size_t)BB*NN*NN*2;
  size_t rem = (ws_size > off) ? (ws_size - off) : 0;
  int tc = (int)(rem / perT);
  if (tc < 1) tc = 1;
  if (tc > 4) tc = 4;

  u16* Abuf = (u16*)(w + off);

  k0_transpose<<<dim3(NN, BB), 256, 0, stream>>>(x, xt);
  kadj<<<dim3((NN*NN)/1024), 256, 0, stream>>>(adj, adjb);
  k1_de<<<dim3(16, BB, TT), 256, 0, stream>>>(xt, Wd, bd, E1, E2, DE1, DE2);

  for (int t0 = 0; t0 < TT; t0 += tc){
    const int nt = (t0 + tc <= TT) ? tc : (TT - t0);
    k23<<<dim3(16, BB, nt), 256, 0, stream>>>(DE1, DE2, Abuf, rowsum, t0);
    k3b<<<dim3(8, BB, nt), 256, 0, stream>>>(xt, Wd, Ws, W0, bd, bs, b0,
                                             rowsum, xdwT, xswT, x0w, t0);
    k4 <<<dim3(8, BB, nt), 512, 0, stream>>>(Abuf, adjb, xdwT, xswT,
                                             rowsum, outT, t0);
  }
  k5<<<dim3(NN/16, BB), 256, 0, stream>>>(outT, x0w, out);
}